// Round 13
// baseline (378.032 us; speedup 1.0000x reference)
//
#include <hip/hip_runtime.h>
#include <math.h>

#define N_VOX 200000
#define CCH   128
#define KOFF  27

typedef __attribute__((ext_vector_type(8))) short bf16x8;
typedef __attribute__((ext_vector_type(4))) float f32x4;

__device__ __forceinline__ float silu_f(float x) {
    return x / (1.0f + expf(-x));
}
__device__ __forceinline__ unsigned short f2bf(float x) {
    unsigned int u = __float_as_uint(x);
    u = (u + 0x7FFFu + ((u >> 16) & 1u)) >> 16;
    return (unsigned short)u;
}
// bijective XCD-aware block swizzle (m204 variant)
__device__ __forceinline__ int xcd_swz(int orig, int nwg) {
    int q = nwg >> 3, r = nwg & 7;
    int xcd = orig & 7, pos = orig >> 3;
    return (xcd < r ? xcd * (q + 1) : r * (q + 1) + (xcd - r) * q) + pos;
}
// async 16B global -> LDS (direct-to-shared DMA)
__device__ __forceinline__ void gload_lds16(const void* g, void* l) {
    __builtin_amdgcn_global_load_lds(
        (const __attribute__((address_space(1))) unsigned int*)g,
        (__attribute__((address_space(3))) unsigned int*)l, 16, 0, 0);
}

// ---------------------------------------------------------------------------
// Kernel 1: time embedding -> bf16 xeb[(N+1)][8] = {feat, sin*3, cos*3, 0}
// ---------------------------------------------------------------------------
__global__ void embed_kernel(const float* __restrict__ feat,
                             const int* __restrict__ t,
                             unsigned short* __restrict__ xeb) {
    int i = blockIdx.x * blockDim.x + threadIdx.x;
    if (i > N_VOX) return;
    union { unsigned short u[8]; int4 v; } o;
    if (i == N_VOX) {
        o.v = make_int4(0, 0, 0, 0);
    } else {
        o.u[0] = f2bf(feat[i]);
        float tf = (float)t[i];
#pragma unroll
        for (int kk = 0; kk < 3; ++kk) {
            float freq = (float)M_PI * (float)(1 << kk);
            float ang = tf * freq;
            o.u[1 + kk] = f2bf(sinf(ang));
            o.u[4 + kk] = f2bf(cosf(ang));
        }
        o.u[7] = 0;
    }
    *(int4*)(xeb + (size_t)i * 8) = o.v;
}

// ---------------------------------------------------------------------------
// Weight repacks to MFMA-fragment-linear bf16 (B-operand layout).
// ---------------------------------------------------------------------------
__global__ void convert_w1(const float* __restrict__ W1,
                           unsigned short* __restrict__ W1f) {
    int g = blockIdx.x * 256 + threadIdx.x;
    if (g >= 7 * 8 * 64) return;
    int l = g & 63;
    int rest = g >> 6;
    int nf = rest & 7;
    int kk = rest >> 3;
    int o = kk * 4 + (l >> 4);
    int co = nf * 16 + (l & 15);
    union { unsigned short u[8]; int4 v; } out;
#pragma unroll
    for (int j = 0; j < 8; ++j) {
        float w = 0.f;
        if (o < KOFF && j < 7) w = W1[((size_t)o * 7 + j) * CCH + co];
        out.u[j] = f2bf(w);
    }
    *(int4*)(W1f + (size_t)g * 8) = out.v;
}

__global__ void convert_w2(const float* __restrict__ W2,
                           unsigned short* __restrict__ W2f) {
    int g = blockIdx.x * 256 + threadIdx.x;
    int l = g & 63;
    int rest = g >> 6;
    int nf = rest & 7;
    int kkk = rest >> 3;
    int k = kkk >> 2, kk = kkk & 3;
    int ci0 = kk * 32 + (l >> 4) * 8;
    int co = nf * 16 + (l & 15);
    union { unsigned short u[8]; int4 v; } out;
#pragma unroll
    for (int j = 0; j < 8; ++j)
        out.u[j] = f2bf(W2[((size_t)k * CCH + ci0 + j) * CCH + co]);
    *(int4*)(W2f + (size_t)g * 8) = out.v;
}

__global__ void convert_w3(const float* __restrict__ W3,
                           unsigned short* __restrict__ W3f) {
    int g = blockIdx.x * 256 + threadIdx.x;
    if (g >= 4 * 8 * 64) return;
    int l = g & 63;
    int rest = g >> 6;
    int nf = rest & 7;
    int kk = rest >> 3;
    int ci0 = kk * 32 + (l >> 4) * 8;
    int co = nf * 16 + (l & 15);
    union { unsigned short u[8]; int4 v; } out;
#pragma unroll
    for (int j = 0; j < 8; ++j)
        out.u[j] = f2bf(W3[(size_t)(ci0 + j) * CCH + co]);
    *(int4*)(W3f + (size_t)g * 8) = out.v;
}

// ---------------------------------------------------------------------------
// Kernel 2: conv1 via MFMA. 128 vox x 128 ch per block, K = 7 steps of 32.
// ---------------------------------------------------------------------------
__global__ __launch_bounds__(256) void conv1_mfma(
    const unsigned short* __restrict__ xeb, const int* __restrict__ nidx,
    const unsigned short* __restrict__ W1f, const float* __restrict__ b1,
    unsigned short* __restrict__ h1b) {
    __shared__ int4 bufmem[2048];
    __shared__ int idxAll[128 * 28];

    int tid = threadIdx.x;
    int l = tid & 63, w = tid >> 6;
    int mw = w >> 1, nwv = w & 1;
    int wg = xcd_swz(blockIdx.x, gridDim.x);
    int v0 = wg * 128;

    for (int g = tid; g < KOFF * 128; g += 256) {
        int k = g >> 7, vi = g & 127;
        int v = v0 + vi;
        idxAll[vi * 28 + k] = (v < N_VOX) ? nidx[(size_t)k * N_VOX + v] : N_VOX;
    }
    if (tid < 128) idxAll[tid * 28 + 27] = N_VOX;
    __syncthreads();

    f32x4 acc[4][4];
#pragma unroll
    for (int m = 0; m < 4; ++m)
#pragma unroll
        for (int n = 0; n < 4; ++n) acc[m][n] = (f32x4)0.f;

    {
        int4 g0[2]; int rr[2], cc[2];
#pragma unroll
        for (int u = 0; u < 2; ++u) {
            int q = u * 256 + tid;
            int r = q >> 2, oo = q & 3;
            int idx = idxAll[r * 28 + oo];
            g0[u] = *(const int4*)(xeb + (size_t)idx * 8);
            rr[u] = r; cc[u] = oo ^ (r & 3);
        }
#pragma unroll
        for (int u = 0; u < 2; ++u) bufmem[rr[u] * 5 + cc[u]] = g0[u];
    }
    __syncthreads();

    for (int kk = 0; kk < 7; ++kk) {
        int cur = kk & 1;
        int4 gg[2]; int rr[2], cc[2];
        if (kk < 6) {
#pragma unroll
            for (int u = 0; u < 2; ++u) {
                int q = u * 256 + tid;
                int r = q >> 2, oo = q & 3;
                int idx = idxAll[r * 28 + (kk + 1) * 4 + oo];
                gg[u] = *(const int4*)(xeb + (size_t)idx * 8);
                rr[u] = r; cc[u] = oo ^ (r & 3);
            }
        }
        bf16x8 a[4], b[4];
#pragma unroll
        for (int n = 0; n < 4; ++n) {
            int nf = nwv * 4 + n;
            b[n] = *(const bf16x8*)(W1f + ((size_t)(kk * 8 + nf) * 64 + l) * 8);
        }
#pragma unroll
        for (int m = 0; m < 4; ++m) {
            int r = mw * 64 + m * 16 + (l & 15);
            int c = l >> 4;
            a[m] = *(const bf16x8*)&bufmem[cur * 640 + r * 5 + (c ^ (r & 3))];
        }
#pragma unroll
        for (int m = 0; m < 4; ++m)
#pragma unroll
            for (int n = 0; n < 4; ++n)
                acc[m][n] = __builtin_amdgcn_mfma_f32_16x16x32_bf16(
                    a[m], b[n], acc[m][n], 0, 0, 0);
        if (kk < 6) {
#pragma unroll
            for (int u = 0; u < 2; ++u)
                bufmem[(cur ^ 1) * 640 + rr[u] * 5 + cc[u]] = gg[u];
        }
        __syncthreads();
    }

    float bias[4];
#pragma unroll
    for (int n = 0; n < 4; ++n) bias[n] = b1[nwv * 64 + n * 16 + (l & 15)];
    unsigned short* H16 = (unsigned short*)bufmem;
#pragma unroll
    for (int m = 0; m < 4; ++m) {
        int rbase = mw * 64 + m * 16 + (l >> 4) * 4;
#pragma unroll
        for (int n = 0; n < 4; ++n) {
            int ch = nwv * 64 + n * 16 + (l & 15);
            int c = ch >> 3;
            f32x4 d = acc[m][n];
#pragma unroll
            for (int ri = 0; ri < 4; ++ri) {
                int r = rbase + ri;
                int s = (c & 8) | ((c & 7) ^ (r & 7));
                H16[r * 128 + s * 8 + (ch & 7)] = f2bf(silu_f(d[ri] + bias[n]));
            }
        }
    }
    __syncthreads();
#pragma unroll
    for (int u = 0; u < 8; ++u) {
        int q = u * 256 + tid;
        int r = q >> 4, s = q & 15;
        int c = (s & 8) | ((s & 7) ^ (r & 7));
        int v = v0 + r;
        if (v < N_VOX)
            *(int4*)(h1b + (size_t)v * CCH + c * 8) = bufmem[r * 16 + s];
    }
    if (blockIdx.x == 0 && tid < 16)
        *(int4*)(h1b + (size_t)N_VOX * CCH + tid * 8) = make_int4(0, 0, 0, 0);
}

// ---------------------------------------------------------------------------
// Kernel 3: conv2, faithful m201-style 8-phase pipeline + fused tail.
// 512 threads (8 waves: 2mw x 4nwv), BM=256, per-wave 128x32 (acc[8][2]).
// BOTH A (gathered) and B (linear) staged via global_load_lds into a 3-deep
// 48KB buffer rotation -> no register VMEM loads in the main loop -> counted
// vmcnt is exact. Per BK=64 step: 4 phases, each {ds_read frags + stage
// quota -> s_barrier -> lgkmcnt(0)+sched_barrier -> setprio 8 MFMA -> 
// s_barrier}. ONE counted wait per step (even vmcnt(7) / odd vmcnt(6)),
// never 0: retires exactly next step's buffer, leaves this step's stages
// in flight (~2 steps of gather-latency budget).
// ---------------------------------------------------------------------------
#define STG_A(P, s3, h, U) {                                               \
    int _T = (U) * 8 + w;                                                  \
    int _r16 = _T >> 1, _kkq = _T & 1;                                     \
    int _idx = idxL[s3][_r16 * 16 + (l & 15)];                             \
    gload_lds16((const char*)h1b + ((size_t)(unsigned)_idx << 8) +         \
                    (h) * 128 + _kkq * 64 + (l >> 4) * 16,                 \
                (void*)&(P)[(U) * 512 + tid]);                             \
}
#define STG_B(P, k2, h, U) {                                               \
    gload_lds16((const char*)W2f + (size_t)(k2) * 32768 + (h) * 16384 +    \
                    (size_t)((U) * 512 + tid) * 16,                        \
                (void*)&(P)[2048 + (U) * 512 + tid]);                      \
}

#define MFMA8(Q) {                                                         \
    __builtin_amdgcn_s_setprio(1);                                         \
    acc[(Q)*2+0][0] = __builtin_amdgcn_mfma_f32_16x16x32_bf16(_a00, bfr[0][0], acc[(Q)*2+0][0], 0, 0, 0); \
    acc[(Q)*2+0][1] = __builtin_amdgcn_mfma_f32_16x16x32_bf16(_a00, bfr[0][1], acc[(Q)*2+0][1], 0, 0, 0); \
    acc[(Q)*2+1][0] = __builtin_amdgcn_mfma_f32_16x16x32_bf16(_a10, bfr[0][0], acc[(Q)*2+1][0], 0, 0, 0); \
    acc[(Q)*2+1][1] = __builtin_amdgcn_mfma_f32_16x16x32_bf16(_a10, bfr[0][1], acc[(Q)*2+1][1], 0, 0, 0); \
    acc[(Q)*2+0][0] = __builtin_amdgcn_mfma_f32_16x16x32_bf16(_a01, bfr[1][0], acc[(Q)*2+0][0], 0, 0, 0); \
    acc[(Q)*2+0][1] = __builtin_amdgcn_mfma_f32_16x16x32_bf16(_a01, bfr[1][1], acc[(Q)*2+0][1], 0, 0, 0); \
    acc[(Q)*2+1][0] = __builtin_amdgcn_mfma_f32_16x16x32_bf16(_a11, bfr[1][0], acc[(Q)*2+1][0], 0, 0, 0); \
    acc[(Q)*2+1][1] = __builtin_amdgcn_mfma_f32_16x16x32_bf16(_a11, bfr[1][1], acc[(Q)*2+1][1], 0, 0, 0); \
    __builtin_amdgcn_s_setprio(0);                                         \
}

#define AREADS(Pc, Q)                                                      \
    bf16x8 _a00 = *(const bf16x8*)&(Pc)[((mw * 8 + (Q)*2 + 0) * 2 + 0) * 64 + l]; \
    bf16x8 _a01 = *(const bf16x8*)&(Pc)[((mw * 8 + (Q)*2 + 0) * 2 + 1) * 64 + l]; \
    bf16x8 _a10 = *(const bf16x8*)&(Pc)[((mw * 8 + (Q)*2 + 1) * 2 + 0) * 64 + l]; \
    bf16x8 _a11 = *(const bf16x8*)&(Pc)[((mw * 8 + (Q)*2 + 1) * 2 + 1) * 64 + l];

#define PHASE(Pc, Q, STAGE_STMTS) {                                        \
    AREADS(Pc, Q)                                                          \
    STAGE_STMTS                                                            \
    asm volatile("s_barrier" ::: "memory");                                \
    asm volatile("s_waitcnt lgkmcnt(0)" ::: "memory");                     \
    __builtin_amdgcn_sched_barrier(0);                                     \
    MFMA8(Q)                                                               \
    asm volatile("s_barrier" ::: "memory");                                \
}

#define PHASE_END(Pc, Q, ENDSTMTS) {                                       \
    AREADS(Pc, Q)                                                          \
    asm volatile("s_barrier" ::: "memory");                                \
    asm volatile("s_waitcnt lgkmcnt(0)" ::: "memory");                     \
    __builtin_amdgcn_sched_barrier(0);                                     \
    MFMA8(Q)                                                               \
    ENDSTMTS                                                               \
    asm volatile("s_barrier" ::: "memory");                                \
}

#define RDB(Pc) {                                                          \
    bfr[0][0] = *(const bf16x8*)&(Pc)[2048 + (0 * 8 + nwv * 2 + 0) * 64 + l]; \
    bfr[0][1] = *(const bf16x8*)&(Pc)[2048 + (0 * 8 + nwv * 2 + 1) * 64 + l]; \
    bfr[1][0] = *(const bf16x8*)&(Pc)[2048 + (1 * 8 + nwv * 2 + 0) * 64 + l]; \
    bfr[1][1] = *(const bf16x8*)&(Pc)[2048 + (1 * 8 + nwv * 2 + 1) * 64 + l]; \
}

__global__ __launch_bounds__(512, 1) void conv2_mfma(
    const unsigned short* __restrict__ h1b, const int* __restrict__ nidx,
    const unsigned short* __restrict__ W2f, const float* __restrict__ b2,
    const unsigned short* __restrict__ W3f, const float* __restrict__ b3,
    const float* __restrict__ W4, const float* __restrict__ b4,
    float* __restrict__ out) {
    __shared__ int4 Pbuf[3][3072];   // 3 x (32KB A + 16KB B) = 144 KB
    __shared__ int idxL[3][256];     // 3 KB rotating idx slots

    int tid = threadIdx.x;
    int l = tid & 63, w = tid >> 6;
    int mw = w >> 2, nwv = w & 3;
    int wg = xcd_swz(blockIdx.x, gridDim.x);
    int v0 = wg * 256;

    // prologue: idx slots 0,1,2 = offsets 0,1,2
    for (int g = tid; g < 3 * 256; g += 512) {
        int k = g >> 8, vi = g & 255;
        int v = v0 + vi;
        idxL[k][vi] = (v < N_VOX) ? nidx[(size_t)k * N_VOX + v] : N_VOX;
    }
    __syncthreads();

    f32x4 acc[8][2];
#pragma unroll
    for (int m = 0; m < 8; ++m)
#pragma unroll
        for (int n = 0; n < 2; ++n) acc[m][n] = (f32x4)0.f;

    int4* P0 = Pbuf[0];
    int4* P1 = Pbuf[1];
    int4* P2 = Pbuf[2];

    // prologue staging: step0 -> P0 (k=0,h=0), step1 -> P1 (k=0,h=1)
    STG_A(P0, 0, 0, 0); STG_A(P0, 0, 0, 1); STG_A(P0, 0, 0, 2); STG_A(P0, 0, 0, 3);
    STG_B(P0, 0, 0, 0); STG_B(P0, 0, 0, 1);
    STG_A(P1, 0, 1, 0); STG_A(P1, 0, 1, 1); STG_A(P1, 0, 1, 2); STG_A(P1, 0, 1, 3);
    STG_B(P1, 0, 1, 0); STG_B(P1, 0, 1, 1);
    asm volatile("s_waitcnt vmcnt(0)" ::: "memory");
    __syncthreads();

    for (int tp = 0; tp < 27; ++tp) {
        int s3 = (tp + 1) % 3;           // idx slot used for staging k2=tp+1
        int k2 = tp + 1;                  // staged offset (27 on last pair: garbage-safe)
        int knew = tp + 2; if (knew > 26) knew = 26;
        int slotw = (tp + 2) % 3;
        int idxreg;
        // ---------------- EVEN step (compute P0, stage -> P2, h=0) --------
        {
            bf16x8 bfr[2][2];
            RDB(P0);
            PHASE(P0, 0, {
                idxreg = nidx[(size_t)knew * N_VOX + v0 + (tid & 255)];
                STG_A(P2, s3, 0, 0); STG_A(P2, s3, 0, 1);
            });
            PHASE(P0, 1, { STG_A(P2, s3, 0, 2); STG_A(P2, s3, 0, 3); });
            PHASE(P0, 2, { STG_B(P2, k2, 0, 0); STG_B(P2, k2, 0, 1); });
            PHASE_END(P0, 3, {
                asm volatile("s_waitcnt vmcnt(7)" ::: "memory");
            });
        }
        // ---------------- ODD step (compute P1, stage -> P0, h=1) ---------
        {
            bf16x8 bfr[2][2];
            RDB(P1);
            PHASE(P1, 0, { STG_A(P0, s3, 1, 0); STG_A(P0, s3, 1, 1); });
            PHASE(P1, 1, { STG_A(P0, s3, 1, 2); STG_A(P0, s3, 1, 3); });
            PHASE(P1, 2, { STG_B(P0, k2, 1, 0); STG_B(P0, k2, 1, 1); });
            PHASE_END(P1, 3, {
                asm volatile("s_waitcnt vmcnt(6)" ::: "memory");
                if (tid < 256) idxL[slotw][tid] = idxreg;
            });
        }
        // rotate: (P0,P1,P2) <- (P2,P0,P1)
        int4* tmp = P0; P0 = P2; P2 = P1; P1 = tmp;
    }
    asm volatile("s_waitcnt vmcnt(0)" ::: "memory");
    __syncthreads();

    // ---- fused tail: H = bf16(silu(acc+b2)) -> LDS; P = H @ W3; out ----
    float bias2[2];
#pragma unroll
    for (int n = 0; n < 2; ++n) bias2[n] = b2[nwv * 32 + n * 16 + (l & 15)];
    unsigned short* H16 = (unsigned short*)&Pbuf[0][0];   // 256x128 = 64 KB
#pragma unroll
    for (int m = 0; m < 8; ++m) {
        int rbase = mw * 128 + m * 16 + (l >> 4) * 4;
#pragma unroll
        for (int n = 0; n < 2; ++n) {
            int ch = nwv * 32 + n * 16 + (l & 15);
            int c = ch >> 3;
            f32x4 d = acc[m][n];
#pragma unroll
            for (int ri = 0; ri < 4; ++ri) {
                int r = rbase + ri;
                int s = (c & 8) | ((c & 7) ^ (r & 7));
                H16[r * 128 + s * 8 + (ch & 7)] = f2bf(silu_f(d[ri] + bias2[n]));
            }
        }
    }
    __syncthreads();

    // W3 GEMM: wave w owns output rows [w*32, w*32+32), N=128 full.
    f32x4 p2[2][8];
#pragma unroll
    for (int m = 0; m < 2; ++m)
#pragma unroll
        for (int n = 0; n < 8; ++n) p2[m][n] = (f32x4)0.f;
#pragma unroll
    for (int kk = 0; kk < 4; ++kk) {
        bf16x8 a[2], b[8];
#pragma unroll
        for (int n = 0; n < 8; ++n)
            b[n] = *(const bf16x8*)(W3f + ((size_t)(kk * 8 + n) * 64 + l) * 8);
#pragma unroll
        for (int m = 0; m < 2; ++m) {
            int r = w * 32 + m * 16 + (l & 15);
            int c = kk * 4 + (l >> 4);
            int s = (c & 8) | ((c & 7) ^ (r & 7));
            a[m] = *(const bf16x8*)&H16[r * 128 + s * 8];
        }
#pragma unroll
        for (int m = 0; m < 2; ++m)
#pragma unroll
            for (int n = 0; n < 8; ++n)
                p2[m][n] = __builtin_amdgcn_mfma_f32_16x16x32_bf16(
                    a[m], b[n], p2[m][n], 0, 0, 0);
    }

#pragma unroll
    for (int m = 0; m < 2; ++m) {
        float po[4] = {0.f, 0.f, 0.f, 0.f};
#pragma unroll
        for (int n = 0; n < 8; ++n) {
            int ch = n * 16 + (l & 15);
            float b3v = b3[ch], w4v = W4[ch];
            f32x4 d = p2[m][n];
#pragma unroll
            for (int ri = 0; ri < 4; ++ri)
                po[ri] += silu_f(d[ri] + b3v) * w4v;
        }
#pragma unroll
        for (int off = 1; off < 16; off <<= 1)
#pragma unroll
            for (int ri = 0; ri < 4; ++ri)
                po[ri] += __shfl_xor(po[ri], off, 64);
        if ((l & 15) == 0) {
            int rbase = v0 + w * 32 + m * 16 + (l >> 4) * 4;
#pragma unroll
            for (int ri = 0; ri < 4; ++ri) {
                int v = rbase + ri;
                if (v < N_VOX) out[v] = po[ri] + b4[0];
            }
        }
    }
}

// ---------------------------------------------------------------------------
extern "C" void kernel_launch(void* const* d_in, const int* in_sizes, int n_in,
                              void* d_out, int out_size, void* d_ws,
                              size_t ws_size, hipStream_t stream) {
    const float* feat = (const float*)d_in[0];
    const int* t      = (const int*)d_in[1];
    const int* nidx   = (const int*)d_in[2];
    const float* W1   = (const float*)d_in[3];
    const float* b1   = (const float*)d_in[4];
    const float* W2   = (const float*)d_in[5];
    const float* b2   = (const float*)d_in[6];
    const float* W3   = (const float*)d_in[7];
    const float* b3   = (const float*)d_in[8];
    const float* W4   = (const float*)d_in[9];
    const float* b4   = (const float*)d_in[10];
    float* out = (float*)d_out;

    char* ws = (char*)d_ws;
    size_t off = 0;
    unsigned short* xeb = (unsigned short*)(ws + off);
    off += ((size_t)(N_VOX + 1) * 8 * 2 + 255) & ~(size_t)255;
    unsigned short* h1b = (unsigned short*)(ws + off);
    off += ((size_t)(N_VOX + 1) * CCH * 2 + 255) & ~(size_t)255;
    unsigned short* W1f = (unsigned short*)(ws + off);
    off += ((size_t)7 * 8 * 64 * 8 * 2 + 255) & ~(size_t)255;
    unsigned short* W2f = (unsigned short*)(ws + off);
    // 28 k-slots (slot 27 staged-but-never-computed by the pipeline tail)
    off += ((size_t)(KOFF + 1) * 4 * 8 * 64 * 8 * 2 + 255) & ~(size_t)255;
    unsigned short* W3f = (unsigned short*)(ws + off);

    int grid1 = (N_VOX + 127) / 128;
    int grid2 = (N_VOX + 255) / 256;
    embed_kernel<<<(N_VOX + 1 + 255) / 256, 256, 0, stream>>>(feat, t, xeb);
    convert_w1<<<(7 * 8 * 64 + 255) / 256, 256, 0, stream>>>(W1, W1f);
    convert_w2<<<(KOFF * 4 * 8 * 64) / 256, 256, 0, stream>>>(W2, W2f);
    convert_w3<<<(4 * 8 * 64 + 255) / 256, 256, 0, stream>>>(W3, W3f);
    conv1_mfma<<<grid1, 256, 0, stream>>>(xeb, nidx, W1f, b1, h1b);
    conv2_mfma<<<grid2, 512, 0, stream>>>(h1b, nidx, W2f, b2, W3f, b3, W4, b4, out);
}